// Round 2
// baseline (215.285 us; speedup 1.0000x reference)
//
#include <hip/hip_runtime.h>

#define BATCH 4
#define NPTS 16384
#define NBOX 128          // M
#define NFEAT 128         // C
#define NS 512            // NUM_SAMPLED
#define ROW 131           // 3 + NFEAT
#define NWORDS (NPTS / 64)   // 256 mask words per box
#define ROWS_PER_BLK 32
#define SUBS (NS / ROWS_PER_BLK)   // 16 gather blocks per box

typedef float v4f __attribute__((ext_vector_type(4)));   // native vec for nt-store

// ---------- Kernel A: per-box ballot + one-shot compaction + wrap ----------
// One block per box. Ballots the 16384-point mask into LDS, compacts ONCE,
// and emits the final wrapped gather indices gidx[NS] (or -1 if empty).
__global__ __launch_bounds__(256) void mask_compact_kernel(
    const float* __restrict__ points,   // [B, N, 3]
    const float* __restrict__ boxes,    // [B, M, 7]
    int* __restrict__ gidx_ws,          // [B*M, NS]
    float* __restrict__ out_flag)       // [B*M]
{
#pragma clang fp contract(off)
    const int box_id = blockIdx.x;
    const int b      = box_id >> 7;
    const int tid    = threadIdx.x;
    const int wave   = tid >> 6;
    const int lane   = tid & 63;

    __shared__ unsigned long long s_bits[NWORDS];  // 2 KB
    __shared__ int s_idx[NS];                      // 2 KB
    __shared__ int s_wsum[4];

    // Box parameters — identical math/order to the verified kernel.
    const float* bx = boxes + box_id * 7;
    const float cx = bx[0], cy = bx[1], cz = bx[2];
    const float hx = bx[3] * 0.5f + 1.0f;
    const float hy = bx[4] * 0.5f + 1.0f;
    const float hz = bx[5] * 0.5f + 1.0f;
    const double hd = (double)bx[6];
    const float ch = (float)cos(hd);
    const float sh = (float)sin(hd);

    const float* pts = points + (size_t)b * NPTS * 3;

    // Wave w owns mask words [w*64, (w+1)*64): word = 64 consecutive points,
    // bit = lane. Same point->bit mapping as the previous ballot kernel.
    #pragma unroll 4
    for (int it = 0; it < 64; ++it) {
        const int word = wave * 64 + it;
        const int i    = word * 64 + lane;
        const float px = pts[i * 3 + 0];
        const float py = pts[i * 3 + 1];
        const float pz = pts[i * 3 + 2];
        const float sx = px - cx;
        const float sy = py - cy;
        const float sz = pz - cz;
        const float t0 = sx * ch;
        const float t1 = sy * sh;
        const float lx = t0 + t1;
        const float t2 = (-sx) * sh;
        const float t3 = sy * ch;
        const float ly = t2 + t3;
        const bool inside = (fabsf(lx) < hx) && (fabsf(ly) < hy) && (fabsf(sz) < hz);
        const unsigned long long m = __ballot(inside);
        if (lane == 0) s_bits[word] = m;
    }
    __syncthreads();

    // ---- compaction: thread t owns mask word t (ascending point order) ----
    const unsigned long long w = s_bits[tid];
    const int pc = __popcll(w);
    int pre = pc;
    #pragma unroll
    for (int off = 1; off < 64; off <<= 1) {
        const int v = __shfl_up(pre, off);
        if (lane >= off) pre += v;
    }
    if (lane == 63) s_wsum[wave] = pre;
    __syncthreads();
    int wbase = 0;
    for (int i = 0; i < wave; ++i) wbase += s_wsum[i];
    const int total = s_wsum[0] + s_wsum[1] + s_wsum[2] + s_wsum[3];
    int pos = wbase + (pre - pc);
    unsigned long long mm = w;
    while (mm && pos < NS) {
        const int bit = __builtin_ctzll(mm);
        s_idx[pos] = tid * 64 + bit;
        ++pos;
        mm &= (mm - 1);
    }
    const int cnt = (total < NS) ? total : NS;
    __syncthreads();

    if (tid == 0) out_flag[box_id] = (cnt == 0) ? 1.0f : 0.0f;

    int* gi = gidx_ws + (size_t)box_id * NS;
    if (cnt == 0) {
        gi[tid]       = -1;
        gi[tid + 256] = -1;
        return;
    }
    {
        int k = tid;
        int j = (k < cnt) ? k : (k % cnt);
        gi[k] = s_idx[j];
        k = tid + 256;
        j = (k < cnt) ? k : (k % cnt);
        gi[k] = s_idx[j];
    }
}

// ---------- Kernel B: pure vectorized gather + streaming nt-store ----------
__global__ __launch_bounds__(256) void gather_kernel(
    const float* __restrict__ points,        // [B, N, 3]
    const float* __restrict__ feats,         // [B, N, C]
    const int*   __restrict__ gidx_ws,       // [B*M, NS]
    float* __restrict__ out_pooled)          // [B, M, NS, ROW]
{
    const int blk    = blockIdx.x;        // box_id * SUBS + sub
    const int box_id = blk >> 4;
    const int sub    = blk & (SUBS - 1);
    const int b      = box_id >> 7;
    const int tid    = threadIdx.x;
    const int wave   = tid >> 6;
    const int lane   = tid & 63;

    __shared__ int s_gi[ROWS_PER_BLK];
    __shared__ float s_row[ROWS_PER_BLK * ROW];   // 16768 B

    if (tid < ROWS_PER_BLK)
        s_gi[tid] = gidx_ws[(size_t)box_id * NS + sub * ROWS_PER_BLK + tid];
    __syncthreads();

    float* outg = out_pooled + (size_t)blk * (ROWS_PER_BLK * ROW);

    if (s_gi[0] < 0) {   // empty box: zero-fill this sub-block
        const v4f z = (v4f)(0.0f);
        v4f* og = (v4f*)outg;
        for (int i = tid; i < (ROWS_PER_BLK * ROW) / 4; i += 256)
            __builtin_nontemporal_store(z, og + i);
        return;
    }

    const float* pts = points + (size_t)b * NPTS * 3;
    const float* fb  = feats  + (size_t)b * NPTS * NFEAT;

    const int cg = lane & 31;   // feature float4-group 0..31
    const int rh = lane >> 5;   // which of the 2 rows this half-wave handles
    #pragma unroll
    for (int it = 0; it < 4; ++it) {
        const int row = wave * 8 + it * 2 + rh;
        const int gi  = s_gi[row];
        const float4 f = *(const float4*)(fb + (size_t)gi * NFEAT + cg * 4);
        float* sr = s_row + row * ROW;
        sr[3 + cg * 4 + 0] = f.x;
        sr[3 + cg * 4 + 1] = f.y;
        sr[3 + cg * 4 + 2] = f.z;
        sr[3 + cg * 4 + 3] = f.w;
        if (cg < 3) sr[cg] = pts[gi * 3 + cg];
    }
    __syncthreads();

    const v4f* sv = (const v4f*)s_row;
    v4f* og = (v4f*)outg;
    for (int i = tid; i < (ROWS_PER_BLK * ROW) / 4; i += 256)
        __builtin_nontemporal_store(sv[i], og + i);
}

extern "C" void kernel_launch(void* const* d_in, const int* in_sizes, int n_in,
                              void* d_out, int out_size, void* d_ws, size_t ws_size,
                              hipStream_t stream) {
    const float* points = (const float*)d_in[0];   // [4,16384,3]
    const float* feats  = (const float*)d_in[1];   // [4,16384,128]
    const float* boxes  = (const float*)d_in[2];   // [4,128,7]
    float* out_pooled = (float*)d_out;
    float* out_flag   = out_pooled + (size_t)BATCH * NBOX * NS * ROW;

    int* gidx_ws = (int*)d_ws;   // 512 boxes * 512 idx * 4 B = 1 MB

    mask_compact_kernel<<<BATCH * NBOX, 256, 0, stream>>>(points, boxes,
                                                          gidx_ws, out_flag);
    gather_kernel<<<BATCH * NBOX * SUBS, 256, 0, stream>>>(points, feats, gidx_ws,
                                                           out_pooled);
}

// Round 3
// 210.029 us; speedup vs baseline: 1.0250x; 1.0250x over previous
//
#include <hip/hip_runtime.h>

#define BATCH 4
#define NPTS 16384
#define NBOX 128          // M
#define NFEAT 128         // C
#define NS 512            // NUM_SAMPLED
#define ROW 131           // 3 + NFEAT
#define NWORDS (NPTS / 64)   // 256 mask words per box
#define ROWS_PER_BLK 32
#define SUBS (NS / ROWS_PER_BLK)   // 16 gather blocks per box

// ---------- Kernel A: per-box ballot + one-shot compaction + wrap ----------
// One block per box. Ballots the 16384-point mask into LDS, compacts ONCE,
// and emits the final wrapped gather indices gidx[NS] (or -1 if empty).
__global__ __launch_bounds__(256) void mask_compact_kernel(
    const float* __restrict__ points,   // [B, N, 3]
    const float* __restrict__ boxes,    // [B, M, 7]
    int* __restrict__ gidx_ws,          // [B*M, NS]
    float* __restrict__ out_flag)       // [B*M]
{
#pragma clang fp contract(off)
    const int box_id = blockIdx.x;
    const int b      = box_id >> 7;
    const int tid    = threadIdx.x;
    const int wave   = tid >> 6;
    const int lane   = tid & 63;

    __shared__ unsigned long long s_bits[NWORDS];  // 2 KB
    __shared__ int s_idx[NS];                      // 2 KB
    __shared__ int s_wsum[4];

    // Box parameters — identical math/order to the verified kernel.
    const float* bx = boxes + box_id * 7;
    const float cx = bx[0], cy = bx[1], cz = bx[2];
    const float hx = bx[3] * 0.5f + 1.0f;
    const float hy = bx[4] * 0.5f + 1.0f;
    const float hz = bx[5] * 0.5f + 1.0f;
    const double hd = (double)bx[6];
    const float ch = (float)cos(hd);
    const float sh = (float)sin(hd);

    const float* pts = points + (size_t)b * NPTS * 3;

    // Wave w owns mask words [w*64, (w+1)*64): word = 64 consecutive points,
    // bit = lane. Same point->bit mapping as the previous ballot kernel.
    #pragma unroll 4
    for (int it = 0; it < 64; ++it) {
        const int word = wave * 64 + it;
        const int i    = word * 64 + lane;
        const float px = pts[i * 3 + 0];
        const float py = pts[i * 3 + 1];
        const float pz = pts[i * 3 + 2];
        const float sx = px - cx;
        const float sy = py - cy;
        const float sz = pz - cz;
        const float t0 = sx * ch;
        const float t1 = sy * sh;
        const float lx = t0 + t1;
        const float t2 = (-sx) * sh;
        const float t3 = sy * ch;
        const float ly = t2 + t3;
        const bool inside = (fabsf(lx) < hx) && (fabsf(ly) < hy) && (fabsf(sz) < hz);
        const unsigned long long m = __ballot(inside);
        if (lane == 0) s_bits[word] = m;
    }
    __syncthreads();

    // ---- compaction: thread t owns mask word t (ascending point order) ----
    const unsigned long long w = s_bits[tid];
    const int pc = __popcll(w);
    int pre = pc;
    #pragma unroll
    for (int off = 1; off < 64; off <<= 1) {
        const int v = __shfl_up(pre, off);
        if (lane >= off) pre += v;
    }
    if (lane == 63) s_wsum[wave] = pre;
    __syncthreads();
    int wbase = 0;
    for (int i = 0; i < wave; ++i) wbase += s_wsum[i];
    const int total = s_wsum[0] + s_wsum[1] + s_wsum[2] + s_wsum[3];
    int pos = wbase + (pre - pc);
    unsigned long long mm = w;
    while (mm && pos < NS) {
        const int bit = __builtin_ctzll(mm);
        s_idx[pos] = tid * 64 + bit;
        ++pos;
        mm &= (mm - 1);
    }
    const int cnt = (total < NS) ? total : NS;
    __syncthreads();

    if (tid == 0) out_flag[box_id] = (cnt == 0) ? 1.0f : 0.0f;

    int* gi = gidx_ws + (size_t)box_id * NS;
    if (cnt == 0) {
        gi[tid]       = -1;
        gi[tid + 256] = -1;
        return;
    }
    {
        int k = tid;
        int j = (k < cnt) ? k : (k % cnt);
        gi[k] = s_idx[j];
        k = tid + 256;
        j = (k < cnt) ? k : (k % cnt);
        gi[k] = s_idx[j];
    }
}

// ---------- Kernel B: pure vectorized gather + coalesced store ------------
__global__ __launch_bounds__(256) void gather_kernel(
    const float* __restrict__ points,        // [B, N, 3]
    const float* __restrict__ feats,         // [B, N, C]
    const int*   __restrict__ gidx_ws,       // [B*M, NS]
    float* __restrict__ out_pooled)          // [B, M, NS, ROW]
{
    const int blk    = blockIdx.x;        // box_id * SUBS + sub
    const int box_id = blk >> 4;
    const int sub    = blk & (SUBS - 1);
    const int b      = box_id >> 7;
    const int tid    = threadIdx.x;
    const int wave   = tid >> 6;
    const int lane   = tid & 63;

    __shared__ int s_gi[ROWS_PER_BLK];
    __shared__ float s_row[ROWS_PER_BLK * ROW];   // 16768 B

    if (tid < ROWS_PER_BLK)
        s_gi[tid] = gidx_ws[(size_t)box_id * NS + sub * ROWS_PER_BLK + tid];
    __syncthreads();

    float* outg = out_pooled + (size_t)blk * (ROWS_PER_BLK * ROW);

    if (s_gi[0] < 0) {   // empty box: zero-fill this sub-block
        const float4 z = make_float4(0.f, 0.f, 0.f, 0.f);
        float4* og = (float4*)outg;
        for (int i = tid; i < (ROWS_PER_BLK * ROW) / 4; i += 256)
            og[i] = z;
        return;
    }

    const float* pts = points + (size_t)b * NPTS * 3;
    const float* fb  = feats  + (size_t)b * NPTS * NFEAT;

    const int cg = lane & 31;   // feature float4-group 0..31
    const int rh = lane >> 5;   // which of the 2 rows this half-wave handles
    #pragma unroll
    for (int it = 0; it < 4; ++it) {
        const int row = wave * 8 + it * 2 + rh;
        const int gi  = s_gi[row];
        const float4 f = *(const float4*)(fb + (size_t)gi * NFEAT + cg * 4);
        float* sr = s_row + row * ROW;
        sr[3 + cg * 4 + 0] = f.x;
        sr[3 + cg * 4 + 1] = f.y;
        sr[3 + cg * 4 + 2] = f.z;
        sr[3 + cg * 4 + 3] = f.w;
        if (cg < 3) sr[cg] = pts[gi * 3 + cg];
    }
    __syncthreads();

    const float4* sv = (const float4*)s_row;
    float4* og = (float4*)outg;
    for (int i = tid; i < (ROWS_PER_BLK * ROW) / 4; i += 256)
        og[i] = sv[i];
}

extern "C" void kernel_launch(void* const* d_in, const int* in_sizes, int n_in,
                              void* d_out, int out_size, void* d_ws, size_t ws_size,
                              hipStream_t stream) {
    const float* points = (const float*)d_in[0];   // [4,16384,3]
    const float* feats  = (const float*)d_in[1];   // [4,16384,128]
    const float* boxes  = (const float*)d_in[2];   // [4,128,7]
    float* out_pooled = (float*)d_out;
    float* out_flag   = out_pooled + (size_t)BATCH * NBOX * NS * ROW;

    int* gidx_ws = (int*)d_ws;   // 512 boxes * 512 idx * 4 B = 1 MB

    mask_compact_kernel<<<BATCH * NBOX, 256, 0, stream>>>(points, boxes,
                                                          gidx_ws, out_flag);
    gather_kernel<<<BATCH * NBOX * SUBS, 256, 0, stream>>>(points, feats, gidx_ws,
                                                           out_pooled);
}

// Round 4
// 191.928 us; speedup vs baseline: 1.1217x; 1.0943x over previous
//
#include <hip/hip_runtime.h>

#define BATCH 4
#define NPTS 16384
#define NBOX 128          // M
#define NFEAT 128         // C
#define NS 512            // NUM_SAMPLED
#define ROW 131           // 3 + NFEAT
#define NWORDS (NPTS / 64)   // 256 mask words per box
#define ROWS_PER_BLK 32
#define SUBS (NS / ROWS_PER_BLK)   // 16 gather blocks per box

// ---------- Kernel A: per-box ballot + one-shot compaction + wrap ----------
// 512 blocks x 1024 threads = full machine (2048 thr/CU), 16 points/thread —
// same ballot parallelism as the 2048-block baseline, but mask words go
// straight to LDS and compaction runs ONCE per box.
__global__ __launch_bounds__(1024) void mask_compact_kernel(
    const float* __restrict__ points,   // [B, N, 3]
    const float* __restrict__ boxes,    // [B, M, 7]
    int* __restrict__ gidx_ws,          // [B*M, NS]
    float* __restrict__ out_flag)       // [B*M]
{
#pragma clang fp contract(off)
    const int box_id = blockIdx.x;
    const int b      = box_id >> 7;
    const int tid    = threadIdx.x;
    const int wave   = tid >> 6;    // 0..15
    const int lane   = tid & 63;

    __shared__ unsigned long long s_bits[NWORDS];  // 2 KB
    __shared__ int s_idx[NS];                      // 2 KB
    __shared__ int s_wsum[4];

    // Box parameters — identical math/order to the verified kernel.
    const float* bx = boxes + box_id * 7;
    const float cx = bx[0], cy = bx[1], cz = bx[2];
    const float hx = bx[3] * 0.5f + 1.0f;
    const float hy = bx[4] * 0.5f + 1.0f;
    const float hz = bx[5] * 0.5f + 1.0f;
    const double hd = (double)bx[6];
    const float ch = (float)cos(hd);
    const float sh = (float)sin(hd);

    const float* pts = points + (size_t)b * NPTS * 3;

    // Wave w owns mask words [w*16, (w+1)*16): word = 64 consecutive points,
    // bit = lane. Same point->bit mapping as before.
    #pragma unroll 4
    for (int it = 0; it < 16; ++it) {
        const int word = wave * 16 + it;
        const int i    = word * 64 + lane;
        const float px = pts[i * 3 + 0];
        const float py = pts[i * 3 + 1];
        const float pz = pts[i * 3 + 2];
        const float sx = px - cx;
        const float sy = py - cy;
        const float sz = pz - cz;
        const float t0 = sx * ch;
        const float t1 = sy * sh;
        const float lx = t0 + t1;
        const float t2 = (-sx) * sh;
        const float t3 = sy * ch;
        const float ly = t2 + t3;
        const bool inside = (fabsf(lx) < hx) && (fabsf(ly) < hy) && (fabsf(sz) < hz);
        const unsigned long long m = __ballot(inside);
        if (lane == 0) s_bits[word] = m;
    }
    __syncthreads();

    // ---- compaction: threads 0..255 each own one mask word ----
    unsigned long long w = 0ull;
    int pc = 0, pre = 0;
    if (tid < 256) {
        w  = s_bits[tid];
        pc = __popcll(w);
        pre = pc;
        #pragma unroll
        for (int off = 1; off < 64; off <<= 1) {
            const int v = __shfl_up(pre, off);
            if (lane >= off) pre += v;
        }
        if (lane == 63) s_wsum[wave] = pre;
    }
    __syncthreads();

    const int total = s_wsum[0] + s_wsum[1] + s_wsum[2] + s_wsum[3];
    const int cnt = (total < NS) ? total : NS;

    if (tid < 256) {
        int wbase = 0;
        for (int i2 = 0; i2 < wave; ++i2) wbase += s_wsum[i2];
        int pos = wbase + (pre - pc);
        unsigned long long mm = w;
        while (mm && pos < NS) {
            const int bit = __builtin_ctzll(mm);
            s_idx[pos] = tid * 64 + bit;
            ++pos;
            mm &= (mm - 1);
        }
    }
    __syncthreads();

    if (tid == 0) out_flag[box_id] = (cnt == 0) ? 1.0f : 0.0f;

    if (tid < NS) {
        int* gi = gidx_ws + (size_t)box_id * NS;
        if (cnt == 0) {
            gi[tid] = -1;
        } else {
            const int j = (tid < cnt) ? tid : (tid % cnt);
            gi[tid] = s_idx[j];
        }
    }
}

// ---------- Kernel B: pure vectorized gather + coalesced store ------------
__global__ __launch_bounds__(256) void gather_kernel(
    const float* __restrict__ points,        // [B, N, 3]
    const float* __restrict__ feats,         // [B, N, C]
    const int*   __restrict__ gidx_ws,       // [B*M, NS]
    float* __restrict__ out_pooled)          // [B, M, NS, ROW]
{
    const int blk    = blockIdx.x;        // box_id * SUBS + sub
    const int box_id = blk >> 4;
    const int sub    = blk & (SUBS - 1);
    const int b      = box_id >> 7;
    const int tid    = threadIdx.x;
    const int wave   = tid >> 6;
    const int lane   = tid & 63;

    __shared__ int s_gi[ROWS_PER_BLK];
    __shared__ float s_row[ROWS_PER_BLK * ROW];   // 16768 B

    if (tid < ROWS_PER_BLK)
        s_gi[tid] = gidx_ws[(size_t)box_id * NS + sub * ROWS_PER_BLK + tid];
    __syncthreads();

    float* outg = out_pooled + (size_t)blk * (ROWS_PER_BLK * ROW);

    if (s_gi[0] < 0) {   // empty box: zero-fill this sub-block
        const float4 z = make_float4(0.f, 0.f, 0.f, 0.f);
        float4* og = (float4*)outg;
        for (int i = tid; i < (ROWS_PER_BLK * ROW) / 4; i += 256)
            og[i] = z;
        return;
    }

    const float* pts = points + (size_t)b * NPTS * 3;
    const float* fb  = feats  + (size_t)b * NPTS * NFEAT;

    const int cg = lane & 31;   // feature float4-group 0..31
    const int rh = lane >> 5;   // which of the 2 rows this half-wave handles
    #pragma unroll
    for (int it = 0; it < 4; ++it) {
        const int row = wave * 8 + it * 2 + rh;
        const int gi  = s_gi[row];
        const float4 f = *(const float4*)(fb + (size_t)gi * NFEAT + cg * 4);
        float* sr = s_row + row * ROW;
        sr[3 + cg * 4 + 0] = f.x;
        sr[3 + cg * 4 + 1] = f.y;
        sr[3 + cg * 4 + 2] = f.z;
        sr[3 + cg * 4 + 3] = f.w;
        if (cg < 3) sr[cg] = pts[gi * 3 + cg];
    }
    __syncthreads();

    const float4* sv = (const float4*)s_row;
    float4* og = (float4*)outg;
    for (int i = tid; i < (ROWS_PER_BLK * ROW) / 4; i += 256)
        og[i] = sv[i];
}

extern "C" void kernel_launch(void* const* d_in, const int* in_sizes, int n_in,
                              void* d_out, int out_size, void* d_ws, size_t ws_size,
                              hipStream_t stream) {
    const float* points = (const float*)d_in[0];   // [4,16384,3]
    const float* feats  = (const float*)d_in[1];   // [4,16384,128]
    const float* boxes  = (const float*)d_in[2];   // [4,128,7]
    float* out_pooled = (float*)d_out;
    float* out_flag   = out_pooled + (size_t)BATCH * NBOX * NS * ROW;

    int* gidx_ws = (int*)d_ws;   // 512 boxes * 512 idx * 4 B = 1 MB

    mask_compact_kernel<<<BATCH * NBOX, 1024, 0, stream>>>(points, boxes,
                                                           gidx_ws, out_flag);
    gather_kernel<<<BATCH * NBOX * SUBS, 256, 0, stream>>>(points, feats, gidx_ws,
                                                           out_pooled);
}